// Round 11
// baseline (973.118 us; speedup 1.0000x reference)
//
#include <hip/hip_runtime.h>
#include <hip/hip_bf16.h>
#include <stdint.h>

typedef unsigned long long u64;

#define N_NODES 10000
#define D_FEAT  128
#define N_EDGES 8192
#define WPR     160       // padded u64 words per packed row (157 valid, pad to 160)
#define WORDS_VALID 157

__device__ __forceinline__ float wave_reduce(float v) {
  #pragma unroll
  for (int o = 32; o > 0; o >>= 1) v += __shfl_xor(v, o, 64);
  return v;
}

// Detect tar_ei element layout per-wave: if the buffer holds int64 (little-endian),
// every odd int32 word is a zero high-word. For genuine int32 indices the odds of
// 64 consecutive odd positions all being 0 are ~0. Returns 2 for int64, 1 for int32.
__device__ __forceinline__ int tar_stride(const int* tar, int lane) {
  int v = tar[2 * lane + 1];
  return (__ballot(v != 0) == 0ull) ? 2 : 1;
}

// K1: per-node projected features yk[n] = x[n,:] . W[(k+1)*128 : (k+2)*128], and zero flags.
__global__ void k_ynode(const float* __restrict__ x, const float* __restrict__ W,
                        float* __restrict__ yn, int* __restrict__ flags) {
  int wid  = (blockIdx.x * blockDim.x + threadIdx.x) >> 6;
  int lane = threadIdx.x & 63;
  if (wid >= N_NODES) return;
  const float* xr = x + (size_t)wid * D_FEAT;
  float x0 = xr[lane], x1 = xr[lane + 64];
  float a0 = x0 * W[128 + lane] + x1 * W[192 + lane];
  float a1 = x0 * W[256 + lane] + x1 * W[320 + lane];
  float a2 = x0 * W[384 + lane] + x1 * W[448 + lane];
  a0 = wave_reduce(a0); a1 = wave_reduce(a1); a2 = wave_reduce(a2);
  if (lane == 0) {
    yn[wid]               = a0;
    yn[N_NODES + wid]     = a1;
    yn[2 * N_NODES + wid] = a2;
    flags[wid] = 0;
  }
}

// K2: mark rows that appear as an edge endpoint (benign write races, all write 1).
__global__ void k_setflags(const int* __restrict__ tar, int* __restrict__ flags) {
  int t    = blockIdx.x * blockDim.x + threadIdx.x;
  int lane = threadIdx.x & 63;
  int stride = tar_stride(tar, lane);
  if (t < 2 * N_EDGES) flags[tar[(size_t)t * stride]] = 1;
}

// K3: bitpack flagged rows via __ballot. One wave per (matrix,row).
// Word w = ballot over lanes of (src[64w + lane] != 0): bit l <- node 64w+l,
// exactly the layout k_edge consumes. Per quad: 4 independent coalesced 256B
// loads + 4 v_cmp (ballot) + one 32B store from lane 0. No LDS, no shuffles,
// no dependent chains (the old bpermute version was ~16-way bank-conflicted:
// 7.7M conflict cycles/dispatch, 25% HBM, 260us).
__global__ void k_bitpack(const float* __restrict__ a0m, const float* __restrict__ a1m,
                          const float* __restrict__ a2m, const int* __restrict__ flags,
                          u64* __restrict__ p0, u64* __restrict__ p1, u64* __restrict__ p2) {
  int wg   = (blockIdx.x * blockDim.x + threadIdx.x) >> 6;
  int lane = threadIdx.x & 63;
  if (wg >= 3 * N_NODES) return;
  int mat = wg / N_NODES;
  int row = wg - mat * N_NODES;
  if (!flags[row]) return;
  const float* src = (mat == 0 ? a0m : mat == 1 ? a1m : a2m) + (size_t)row * N_NODES;
  u64* dst = (mat == 0 ? p0 : mat == 1 ? p1 : p2) + (size_t)row * WPR;

  // 39 quads cover words 0..155 (floats 0..9983)
  for (int q = 0; q < 39; ++q) {
    int base = q * 256 + lane;
    float f0 = src[base];
    float f1 = src[base + 64];
    float f2 = src[base + 128];
    float f3 = src[base + 192];
    u64 b0 = __ballot(f0 != 0.f);
    u64 b1 = __ballot(f1 != 0.f);
    u64 b2 = __ballot(f2 != 0.f);
    u64 b3 = __ballot(f3 != 0.f);
    if (lane == 0) {
      dst[4 * q]     = b0;
      dst[4 * q + 1] = b1;
      dst[4 * q + 2] = b2;
      dst[4 * q + 3] = b3;
    }
  }
  // tail word 156: floats 9984..9999 (16 valid bits, rest 0)
  float ft = (lane < 16) ? src[9984 + lane] : 0.f;
  u64 bt = __ballot(ft != 0.f);
  if (lane == 0) dst[156] = bt;
}

// K4: one wave per edge. AND packed rows, gather yk for set bits, add xij.W0 term, reduce.
__global__ void k_edge(const float* __restrict__ x, const int* __restrict__ tar,
                       const u64* __restrict__ p0, const u64* __restrict__ p1,
                       const u64* __restrict__ p2, const float* __restrict__ yn,
                       const float* __restrict__ W, const float* __restrict__ b,
                       float* __restrict__ out) {
  int e    = (blockIdx.x * blockDim.x + threadIdx.x) >> 6;
  int lane = threadIdx.x & 63;
  int stride = tar_stride(tar, lane);
  if (e >= N_EDGES) return;
  int i = tar[(size_t)e * stride];
  int j = tar[(size_t)(N_EDGES + e) * stride];

  const float* xi = x + (size_t)i * D_FEAT;
  const float* xj = x + (size_t)j * D_FEAT;
  float acc = xi[lane] * xj[lane] * W[lane] + xi[lane + 64] * xj[lane + 64] * W[lane + 64];

  const u64* r0i = p0 + (size_t)i * WPR; const u64* r0j = p0 + (size_t)j * WPR;
  const u64* r1i = p1 + (size_t)i * WPR; const u64* r1j = p1 + (size_t)j * WPR;
  const u64* r2i = p2 + (size_t)i * WPR; const u64* r2j = p2 + (size_t)j * WPR;
  const float* y0 = yn;
  const float* y1 = yn + N_NODES;
  const float* y2 = yn + 2 * N_NODES;

  for (int w = lane; w < WORDS_VALID; w += 64) {
    u64 m01  = r0i[w] & r0j[w];   // cn_0_1
    u64 m1   = r1i[w] & r1j[w];   // cn_1
    u64 m012 = r2i[w] & r2j[w];   // cn_0_1_2
    u64 m0 = m01  & ~m1;          // cn_0 = cn_0_1 * (1 - cn_1)
    u64 m2 = m012 & ~m01;         // cn_2 = cn_0_1_2 * (1 - cn_0_1)
    int base = w << 6;
    while (m0) { int n = __builtin_ctzll(m0); acc += y0[base + n]; m0 &= m0 - 1; }
    while (m1) { int n = __builtin_ctzll(m1); acc += y1[base + n]; m1 &= m1 - 1; }
    while (m2) { int n = __builtin_ctzll(m2); acc += y2[base + n]; m2 &= m2 - 1; }
  }
  acc = wave_reduce(acc);
  if (lane == 0) out[e] = acc + b[0];
}

// Fallback (no workspace): wave per edge, stream float adjacency rows directly.
__global__ void k_edge_direct(const float* __restrict__ x, const int* __restrict__ tar,
                              const float* __restrict__ a0m, const float* __restrict__ a1m,
                              const float* __restrict__ a2m, const float* __restrict__ W,
                              const float* __restrict__ b, float* __restrict__ out) {
  int e    = (blockIdx.x * blockDim.x + threadIdx.x) >> 6;
  int lane = threadIdx.x & 63;
  int stride = tar_stride(tar, lane);
  if (e >= N_EDGES) return;
  int i = tar[(size_t)e * stride];
  int j = tar[(size_t)(N_EDGES + e) * stride];
  const float* xi = x + (size_t)i * D_FEAT;
  const float* xj = x + (size_t)j * D_FEAT;
  float acc = xi[lane] * xj[lane] * W[lane] + xi[lane + 64] * xj[lane + 64] * W[lane + 64];
  const float* r0i = a0m + (size_t)i * N_NODES; const float* r0j = a0m + (size_t)j * N_NODES;
  const float* r1i = a1m + (size_t)i * N_NODES; const float* r1j = a1m + (size_t)j * N_NODES;
  const float* r2i = a2m + (size_t)i * N_NODES; const float* r2j = a2m + (size_t)j * N_NODES;
  for (int n = lane; n < N_NODES; n += 64) {
    float c01  = r0i[n] * r0j[n];
    float c1   = r1i[n] * r1j[n];
    float c012 = r2i[n] * r2j[n];
    float c0 = c01  * (1.f - c1);
    float c2 = c012 * (1.f - c01);
    if (c0 != 0.f || c1 != 0.f || c2 != 0.f) {
      const float* xn = x + (size_t)n * D_FEAT;
      float s = 0.f;
      for (int d = 0; d < D_FEAT; ++d)
        s += (c0 * W[128 + d] + c1 * W[256 + d] + c2 * W[384 + d]) * xn[d];
      acc += s;
    }
  }
  acc = wave_reduce(acc);
  if (lane == 0) out[e] = acc + b[0];
}

extern "C" void kernel_launch(void* const* d_in, const int* in_sizes, int n_in,
                              void* d_out, int out_size, void* d_ws, size_t ws_size,
                              hipStream_t stream) {
  const float* x    = (const float*)d_in[0];
  const float* a01  = (const float*)d_in[1];
  const float* a1   = (const float*)d_in[2];
  const float* a012 = (const float*)d_in[3];
  const int*   tar  = (const int*)d_in[4];
  const float* W    = (const float*)d_in[5];
  const float* b    = (const float*)d_in[6];
  float* out = (float*)d_out;

  const size_t packed_words = (size_t)N_NODES * WPR;       // per matrix
  const size_t need = 3 * packed_words * sizeof(u64)
                    + 3 * N_NODES * sizeof(float)
                    + N_NODES * sizeof(int);

  if (ws_size >= need) {
    u64* p0 = (u64*)d_ws;
    u64* p1 = p0 + packed_words;
    u64* p2 = p1 + packed_words;
    float* yn  = (float*)(p2 + packed_words);
    int* flags = (int*)(yn + 3 * N_NODES);

    k_ynode   <<<(N_NODES + 3) / 4, 256, 0, stream>>>(x, W, yn, flags);
    k_setflags<<<(2 * N_EDGES + 255) / 256, 256, 0, stream>>>(tar, flags);
    k_bitpack <<<(3 * N_NODES + 3) / 4, 256, 0, stream>>>(a01, a1, a012, flags, p0, p1, p2);
    k_edge    <<<(N_EDGES + 3) / 4, 256, 0, stream>>>(x, tar, p0, p1, p2, yn, W, b, out);
  } else {
    k_edge_direct<<<(N_EDGES + 3) / 4, 256, 0, stream>>>(x, tar, a01, a1, a012, W, b, out);
  }
}

// Round 12
// 966.880 us; speedup vs baseline: 1.0065x; 1.0065x over previous
//
#include <hip/hip_runtime.h>
#include <hip/hip_bf16.h>
#include <stdint.h>

typedef unsigned long long u64;

#define N_NODES 10000
#define D_FEAT  128
#define N_EDGES 8192
#define WPR     160       // padded u64 words per packed row (157 valid, pad to 160)
#define WORDS_VALID 157

__device__ __forceinline__ float wave_reduce(float v) {
  #pragma unroll
  for (int o = 32; o > 0; o >>= 1) v += __shfl_xor(v, o, 64);
  return v;
}

// Detect tar_ei element layout per-wave: if the buffer holds int64 (little-endian),
// every odd int32 word is a zero high-word. For genuine int32 indices the odds of
// 64 consecutive odd positions all being 0 are ~0. Returns 2 for int64, 1 for int32.
__device__ __forceinline__ int tar_stride(const int* tar, int lane) {
  int v = tar[2 * lane + 1];
  return (__ballot(v != 0) == 0ull) ? 2 : 1;
}

// K1: per-node projected features yk[n] = x[n,:] . W[(k+1)*128 : (k+2)*128], and zero flags.
__global__ void k_ynode(const float* __restrict__ x, const float* __restrict__ W,
                        float* __restrict__ yn, int* __restrict__ flags) {
  int wid  = (blockIdx.x * blockDim.x + threadIdx.x) >> 6;
  int lane = threadIdx.x & 63;
  if (wid >= N_NODES) return;
  const float* xr = x + (size_t)wid * D_FEAT;
  float x0 = xr[lane], x1 = xr[lane + 64];
  float a0 = x0 * W[128 + lane] + x1 * W[192 + lane];
  float a1 = x0 * W[256 + lane] + x1 * W[320 + lane];
  float a2 = x0 * W[384 + lane] + x1 * W[448 + lane];
  a0 = wave_reduce(a0); a1 = wave_reduce(a1); a2 = wave_reduce(a2);
  if (lane == 0) {
    yn[wid]               = a0;
    yn[N_NODES + wid]     = a1;
    yn[2 * N_NODES + wid] = a2;
    flags[wid] = 0;
  }
}

// K2: mark rows that appear as an edge endpoint (benign write races, all write 1).
__global__ void k_setflags(const int* __restrict__ tar, int* __restrict__ flags) {
  int t    = blockIdx.x * blockDim.x + threadIdx.x;
  int lane = threadIdx.x & 63;
  int stride = tar_stride(tar, lane);
  if (t < 2 * N_EDGES) flags[tar[(size_t)t * stride]] = 1;
}

// K3: bitpack flagged rows via __ballot, MLP-batched. One wave per (matrix,row).
// Word w = ballot over lanes of (src[64w + lane] != 0) - layout k_edge consumes.
// Round-11 lesson: 4 loads in flight (1KB/wave) pinned the kernel at 2 TB/s,
// latency-bound (262us, 25% HBM, conflicts already 0). Batch 16 independent
// loads (4KB/wave in flight) before the ballots consume them; static unrolled
// register arrays only (runtime-indexed arrays would spill to scratch).
__global__ void k_bitpack(const float* __restrict__ a0m, const float* __restrict__ a1m,
                          const float* __restrict__ a2m, const int* __restrict__ flags,
                          u64* __restrict__ p0, u64* __restrict__ p1, u64* __restrict__ p2) {
  int wg   = (blockIdx.x * blockDim.x + threadIdx.x) >> 6;
  int lane = threadIdx.x & 63;
  if (wg >= 3 * N_NODES) return;
  int mat = wg / N_NODES;
  int row = wg - mat * N_NODES;
  if (!flags[row]) return;
  const float* src = (mat == 0 ? a0m : mat == 1 ? a1m : a2m) + (size_t)row * N_NODES;
  u64* dst = (mat == 0 ? p0 : mat == 1 ? p1 : p2) + (size_t)row * WPR;

  // 9 blocks x 16 words = words 0..143 (floats 0..9215), all in-bounds.
  for (int blk = 0; blk < 9; ++blk) {
    const float* s0 = src + blk * 1024 + lane;
    float f[16];
    u64 bb[16];
    #pragma unroll
    for (int t = 0; t < 16; ++t) f[t] = s0[t * 64];       // 16 independent loads in flight
    #pragma unroll
    for (int t = 0; t < 16; ++t) bb[t] = __ballot(f[t] != 0.f);
    if (lane == 0) {
      u64* d = dst + blk * 16;
      #pragma unroll
      for (int t = 0; t < 16; ++t) d[t] = bb[t];
    }
  }
  // tail: words 144..156 (floats 9216..9999; word 156 has 16 valid bits)
  {
    float f[13];
    u64 bb[13];
    #pragma unroll
    for (int t = 0; t < 12; ++t) f[t] = src[(144 + t) * 64 + lane];
    f[12] = (lane < 16) ? src[9984 + lane] : 0.f;
    #pragma unroll
    for (int t = 0; t < 13; ++t) bb[t] = __ballot(f[t] != 0.f);
    if (lane == 0) {
      #pragma unroll
      for (int t = 0; t < 13; ++t) dst[144 + t] = bb[t];
    }
  }
}

// K4: one wave per edge. AND packed rows, gather yk for set bits, add xij.W0 term, reduce.
__global__ void k_edge(const float* __restrict__ x, const int* __restrict__ tar,
                       const u64* __restrict__ p0, const u64* __restrict__ p1,
                       const u64* __restrict__ p2, const float* __restrict__ yn,
                       const float* __restrict__ W, const float* __restrict__ b,
                       float* __restrict__ out) {
  int e    = (blockIdx.x * blockDim.x + threadIdx.x) >> 6;
  int lane = threadIdx.x & 63;
  int stride = tar_stride(tar, lane);
  if (e >= N_EDGES) return;
  int i = tar[(size_t)e * stride];
  int j = tar[(size_t)(N_EDGES + e) * stride];

  const float* xi = x + (size_t)i * D_FEAT;
  const float* xj = x + (size_t)j * D_FEAT;
  float acc = xi[lane] * xj[lane] * W[lane] + xi[lane + 64] * xj[lane + 64] * W[lane + 64];

  const u64* r0i = p0 + (size_t)i * WPR; const u64* r0j = p0 + (size_t)j * WPR;
  const u64* r1i = p1 + (size_t)i * WPR; const u64* r1j = p1 + (size_t)j * WPR;
  const u64* r2i = p2 + (size_t)i * WPR; const u64* r2j = p2 + (size_t)j * WPR;
  const float* y0 = yn;
  const float* y1 = yn + N_NODES;
  const float* y2 = yn + 2 * N_NODES;

  for (int w = lane; w < WORDS_VALID; w += 64) {
    u64 m01  = r0i[w] & r0j[w];   // cn_0_1
    u64 m1   = r1i[w] & r1j[w];   // cn_1
    u64 m012 = r2i[w] & r2j[w];   // cn_0_1_2
    u64 m0 = m01  & ~m1;          // cn_0 = cn_0_1 * (1 - cn_1)
    u64 m2 = m012 & ~m01;         // cn_2 = cn_0_1_2 * (1 - cn_0_1)
    int base = w << 6;
    while (m0) { int n = __builtin_ctzll(m0); acc += y0[base + n]; m0 &= m0 - 1; }
    while (m1) { int n = __builtin_ctzll(m1); acc += y1[base + n]; m1 &= m1 - 1; }
    while (m2) { int n = __builtin_ctzll(m2); acc += y2[base + n]; m2 &= m2 - 1; }
  }
  acc = wave_reduce(acc);
  if (lane == 0) out[e] = acc + b[0];
}

// Fallback (no workspace): wave per edge, stream float adjacency rows directly.
__global__ void k_edge_direct(const float* __restrict__ x, const int* __restrict__ tar,
                              const float* __restrict__ a0m, const float* __restrict__ a1m,
                              const float* __restrict__ a2m, const float* __restrict__ W,
                              const float* __restrict__ b, float* __restrict__ out) {
  int e    = (blockIdx.x * blockDim.x + threadIdx.x) >> 6;
  int lane = threadIdx.x & 63;
  int stride = tar_stride(tar, lane);
  if (e >= N_EDGES) return;
  int i = tar[(size_t)e * stride];
  int j = tar[(size_t)(N_EDGES + e) * stride];
  const float* xi = x + (size_t)i * D_FEAT;
  const float* xj = x + (size_t)j * D_FEAT;
  float acc = xi[lane] * xj[lane] * W[lane] + xi[lane + 64] * xj[lane + 64] * W[lane + 64];
  const float* r0i = a0m + (size_t)i * N_NODES; const float* r0j = a0m + (size_t)j * N_NODES;
  const float* r1i = a1m + (size_t)i * N_NODES; const float* r1j = a1m + (size_t)j * N_NODES;
  const float* r2i = a2m + (size_t)i * N_NODES; const float* r2j = a2m + (size_t)j * N_NODES;
  for (int n = lane; n < N_NODES; n += 64) {
    float c01  = r0i[n] * r0j[n];
    float c1   = r1i[n] * r1j[n];
    float c012 = r2i[n] * r2j[n];
    float c0 = c01  * (1.f - c1);
    float c2 = c012 * (1.f - c01);
    if (c0 != 0.f || c1 != 0.f || c2 != 0.f) {
      const float* xn = x + (size_t)n * D_FEAT;
      float s = 0.f;
      for (int d = 0; d < D_FEAT; ++d)
        s += (c0 * W[128 + d] + c1 * W[256 + d] + c2 * W[384 + d]) * xn[d];
      acc += s;
    }
  }
  acc = wave_reduce(acc);
  if (lane == 0) out[e] = acc + b[0];
}

extern "C" void kernel_launch(void* const* d_in, const int* in_sizes, int n_in,
                              void* d_out, int out_size, void* d_ws, size_t ws_size,
                              hipStream_t stream) {
  const float* x    = (const float*)d_in[0];
  const float* a01  = (const float*)d_in[1];
  const float* a1   = (const float*)d_in[2];
  const float* a012 = (const float*)d_in[3];
  const int*   tar  = (const int*)d_in[4];
  const float* W    = (const float*)d_in[5];
  const float* b    = (const float*)d_in[6];
  float* out = (float*)d_out;

  const size_t packed_words = (size_t)N_NODES * WPR;       // per matrix
  const size_t need = 3 * packed_words * sizeof(u64)
                    + 3 * N_NODES * sizeof(float)
                    + N_NODES * sizeof(int);

  if (ws_size >= need) {
    u64* p0 = (u64*)d_ws;
    u64* p1 = p0 + packed_words;
    u64* p2 = p1 + packed_words;
    float* yn  = (float*)(p2 + packed_words);
    int* flags = (int*)(yn + 3 * N_NODES);

    k_ynode   <<<(N_NODES + 3) / 4, 256, 0, stream>>>(x, W, yn, flags);
    k_setflags<<<(2 * N_EDGES + 255) / 256, 256, 0, stream>>>(tar, flags);
    k_bitpack <<<(3 * N_NODES + 3) / 4, 256, 0, stream>>>(a01, a1, a012, flags, p0, p1, p2);
    k_edge    <<<(N_EDGES + 3) / 4, 256, 0, stream>>>(x, tar, p0, p1, p2, yn, W, b, out);
  } else {
    k_edge_direct<<<(N_EDGES + 3) / 4, 256, 0, stream>>>(x, tar, a01, a1, a012, W, b, out);
  }
}

// Round 14
// 963.804 us; speedup vs baseline: 1.0097x; 1.0032x over previous
//
#include <hip/hip_runtime.h>
#include <hip/hip_bf16.h>
#include <stdint.h>

typedef unsigned long long u64;

#define N_NODES 10000
#define D_FEAT  128
#define N_EDGES 8192
#define WPR     160       // u64 words per packed row (all 160 valid in float4 layout)

__device__ __forceinline__ float wave_reduce(float v) {
  #pragma unroll
  for (int o = 32; o > 0; o >>= 1) v += __shfl_xor(v, o, 64);
  return v;
}

// Detect tar_ei element layout per-wave: if the buffer holds int64 (little-endian),
// every odd int32 word is a zero high-word. For genuine int32 indices the odds of
// 64 consecutive odd positions all being 0 are ~0. Returns 2 for int64, 1 for int32.
__device__ __forceinline__ int tar_stride(const int* tar, int lane) {
  int v = tar[2 * lane + 1];
  return (__ballot(v != 0) == 0ull) ? 2 : 1;
}

// K1: per-node projected features yk[n] = x[n,:] . W[(k+1)*128 : (k+2)*128], and zero flags.
__global__ void k_ynode(const float* __restrict__ x, const float* __restrict__ W,
                        float* __restrict__ yn, int* __restrict__ flags) {
  int wid  = (blockIdx.x * blockDim.x + threadIdx.x) >> 6;
  int lane = threadIdx.x & 63;
  if (wid >= N_NODES) return;
  const float* xr = x + (size_t)wid * D_FEAT;
  float x0 = xr[lane], x1 = xr[lane + 64];
  float a0 = x0 * W[128 + lane] + x1 * W[192 + lane];
  float a1 = x0 * W[256 + lane] + x1 * W[320 + lane];
  float a2 = x0 * W[384 + lane] + x1 * W[448 + lane];
  a0 = wave_reduce(a0); a1 = wave_reduce(a1); a2 = wave_reduce(a2);
  if (lane == 0) {
    yn[wid]               = a0;
    yn[N_NODES + wid]     = a1;
    yn[2 * N_NODES + wid] = a2;
    flags[wid] = 0;
  }
}

// K2: mark rows that appear as an edge endpoint (benign write races, all write 1).
__global__ void k_setflags(const int* __restrict__ tar, int* __restrict__ flags) {
  int t    = blockIdx.x * blockDim.x + threadIdx.x;
  int lane = threadIdx.x & 63;
  int stride = tar_stride(tar, lane);
  if (t < 2 * N_EDGES) flags[tar[(size_t)t * stride]] = 1;
}

// K3: bitpack via float4 loads + ballot. One wave per (matrix,row).
// Rounds 9/11/12 all landed at ~256us / 2 TB/s with dword loads regardless of
// structure (conflicts 0, MLP batch defeated by regalloc, VGPR=16) -> the
// invariant was the 4B/lane load width. Here each instruction moves 16B/lane
// (1KB/wave), 4 chunks batched -> 4KB/wave in flight minimum.
// LAYOUT (changed, k_edge matches): chunk q = floats 256q..256q+255; lane l
// holds floats 256q+4l+c; word 4q+c = ballot(component c != 0)
//   => bit n of word w  <->  float/node 256*(w>>2) + 4*n + (w&3).
__global__ void k_bitpack(const float* __restrict__ a0m, const float* __restrict__ a1m,
                          const float* __restrict__ a2m, const int* __restrict__ flags,
                          u64* __restrict__ p0, u64* __restrict__ p1, u64* __restrict__ p2) {
  int wg   = (blockIdx.x * blockDim.x + threadIdx.x) >> 6;
  int lane = threadIdx.x & 63;
  if (wg >= 3 * N_NODES) return;
  int mat = wg / N_NODES;
  int row = wg - mat * N_NODES;
  if (!flags[row]) return;
  const float4* src4 = reinterpret_cast<const float4*>(
      (mat == 0 ? a0m : mat == 1 ? a1m : a2m) + (size_t)row * N_NODES);
  u64* dst = (mat == 0 ? p0 : mat == 1 ? p1 : p2) + (size_t)row * WPR;

  // 9 iters x 4 chunks = chunks 0..35 (floats 0..9215), words 0..143.
  for (int it = 0; it < 9; ++it) {
    const float4* s = src4 + (it << 8) + lane;   // 4 chunks = 256 float4
    float4 f0 = s[0];
    float4 f1 = s[64];
    float4 f2 = s[128];
    float4 f3 = s[192];
    u64 bb[16];
    bb[0]  = __ballot(f0.x != 0.f); bb[1]  = __ballot(f0.y != 0.f);
    bb[2]  = __ballot(f0.z != 0.f); bb[3]  = __ballot(f0.w != 0.f);
    bb[4]  = __ballot(f1.x != 0.f); bb[5]  = __ballot(f1.y != 0.f);
    bb[6]  = __ballot(f1.z != 0.f); bb[7]  = __ballot(f1.w != 0.f);
    bb[8]  = __ballot(f2.x != 0.f); bb[9]  = __ballot(f2.y != 0.f);
    bb[10] = __ballot(f2.z != 0.f); bb[11] = __ballot(f2.w != 0.f);
    bb[12] = __ballot(f3.x != 0.f); bb[13] = __ballot(f3.y != 0.f);
    bb[14] = __ballot(f3.z != 0.f); bb[15] = __ballot(f3.w != 0.f);
    if (lane == 0) {
      u64* d = dst + (it << 4);
      #pragma unroll
      for (int t = 0; t < 16; ++t) d[t] = bb[t];
    }
  }
  // Epilogue: chunks 36,37,38 (floats 9216..9983) + tail chunk 39
  // (floats 9984..9999, only lanes 0..3 valid) -> words 144..159.
  {
    const float4* s = src4 + (36 << 6) + lane;   // 36*64 = 2304
    float4 f0 = s[0];
    float4 f1 = s[64];
    float4 f2 = s[128];
    float4 f3 = (lane < 4) ? src4[2496 + lane] : make_float4(0.f, 0.f, 0.f, 0.f);
    u64 bb[16];
    bb[0]  = __ballot(f0.x != 0.f); bb[1]  = __ballot(f0.y != 0.f);
    bb[2]  = __ballot(f0.z != 0.f); bb[3]  = __ballot(f0.w != 0.f);
    bb[4]  = __ballot(f1.x != 0.f); bb[5]  = __ballot(f1.y != 0.f);
    bb[6]  = __ballot(f1.z != 0.f); bb[7]  = __ballot(f1.w != 0.f);
    bb[8]  = __ballot(f2.x != 0.f); bb[9]  = __ballot(f2.y != 0.f);
    bb[10] = __ballot(f2.z != 0.f); bb[11] = __ballot(f2.w != 0.f);
    bb[12] = __ballot(f3.x != 0.f); bb[13] = __ballot(f3.y != 0.f);
    bb[14] = __ballot(f3.z != 0.f); bb[15] = __ballot(f3.w != 0.f);
    if (lane == 0) {
      #pragma unroll
      for (int t = 0; t < 16; ++t) dst[144 + t] = bb[t];
    }
  }
}

// K4: one wave per edge. AND packed rows, gather yk for set bits, add xij.W0 term, reduce.
// Gather index matches the float4 bit layout: node = ((w>>2)<<8) + 4*bit + (w&3).
__global__ void k_edge(const float* __restrict__ x, const int* __restrict__ tar,
                       const u64* __restrict__ p0, const u64* __restrict__ p1,
                       const u64* __restrict__ p2, const float* __restrict__ yn,
                       const float* __restrict__ W, const float* __restrict__ b,
                       float* __restrict__ out) {
  int e    = (blockIdx.x * blockDim.x + threadIdx.x) >> 6;
  int lane = threadIdx.x & 63;
  int stride = tar_stride(tar, lane);
  if (e >= N_EDGES) return;
  int i = tar[(size_t)e * stride];
  int j = tar[(size_t)(N_EDGES + e) * stride];

  const float* xi = x + (size_t)i * D_FEAT;
  const float* xj = x + (size_t)j * D_FEAT;
  float acc = xi[lane] * xj[lane] * W[lane] + xi[lane + 64] * xj[lane + 64] * W[lane + 64];

  const u64* r0i = p0 + (size_t)i * WPR; const u64* r0j = p0 + (size_t)j * WPR;
  const u64* r1i = p1 + (size_t)i * WPR; const u64* r1j = p1 + (size_t)j * WPR;
  const u64* r2i = p2 + (size_t)i * WPR; const u64* r2j = p2 + (size_t)j * WPR;
  const float* y0 = yn;
  const float* y1 = yn + N_NODES;
  const float* y2 = yn + 2 * N_NODES;

  for (int w = lane; w < WPR; w += 64) {
    u64 m01  = r0i[w] & r0j[w];   // cn_0_1
    u64 m1   = r1i[w] & r1j[w];   // cn_1
    u64 m012 = r2i[w] & r2j[w];   // cn_0_1_2
    u64 m0 = m01  & ~m1;          // cn_0 = cn_0_1 * (1 - cn_1)
    u64 m2 = m012 & ~m01;         // cn_2 = cn_0_1_2 * (1 - cn_0_1)
    int base = (w >> 2) << 8;
    int c    = w & 3;
    while (m0) { int n = __builtin_ctzll(m0); acc += y0[base + (n << 2) + c]; m0 &= m0 - 1; }
    while (m1) { int n = __builtin_ctzll(m1); acc += y1[base + (n << 2) + c]; m1 &= m1 - 1; }
    while (m2) { int n = __builtin_ctzll(m2); acc += y2[base + (n << 2) + c]; m2 &= m2 - 1; }
  }
  acc = wave_reduce(acc);
  if (lane == 0) out[e] = acc + b[0];
}

// Fallback (no workspace): wave per edge, stream float adjacency rows directly.
__global__ void k_edge_direct(const float* __restrict__ x, const int* __restrict__ tar,
                              const float* __restrict__ a0m, const float* __restrict__ a1m,
                              const float* __restrict__ a2m, const float* __restrict__ W,
                              const float* __restrict__ b, float* __restrict__ out) {
  int e    = (blockIdx.x * blockDim.x + threadIdx.x) >> 6;
  int lane = threadIdx.x & 63;
  int stride = tar_stride(tar, lane);
  if (e >= N_EDGES) return;
  int i = tar[(size_t)e * stride];
  int j = tar[(size_t)(N_EDGES + e) * stride];
  const float* xi = x + (size_t)i * D_FEAT;
  const float* xj = x + (size_t)j * D_FEAT;
  float acc = xi[lane] * xj[lane] * W[lane] + xi[lane + 64] * xj[lane + 64] * W[lane + 64];
  const float* r0i = a0m + (size_t)i * N_NODES; const float* r0j = a0m + (size_t)j * N_NODES;
  const float* r1i = a1m + (size_t)i * N_NODES; const float* r1j = a1m + (size_t)j * N_NODES;
  const float* r2i = a2m + (size_t)i * N_NODES; const float* r2j = a2m + (size_t)j * N_NODES;
  for (int n = lane; n < N_NODES; n += 64) {
    float c01  = r0i[n] * r0j[n];
    float c1   = r1i[n] * r1j[n];
    float c012 = r2i[n] * r2j[n];
    float c0 = c01  * (1.f - c1);
    float c2 = c012 * (1.f - c01);
    if (c0 != 0.f || c1 != 0.f || c2 != 0.f) {
      const float* xn = x + (size_t)n * D_FEAT;
      float s = 0.f;
      for (int d = 0; d < D_FEAT; ++d)
        s += (c0 * W[128 + d] + c1 * W[256 + d] + c2 * W[384 + d]) * xn[d];
      acc += s;
    }
  }
  acc = wave_reduce(acc);
  if (lane == 0) out[e] = acc + b[0];
}

extern "C" void kernel_launch(void* const* d_in, const int* in_sizes, int n_in,
                              void* d_out, int out_size, void* d_ws, size_t ws_size,
                              hipStream_t stream) {
  const float* x    = (const float*)d_in[0];
  const float* a01  = (const float*)d_in[1];
  const float* a1   = (const float*)d_in[2];
  const float* a012 = (const float*)d_in[3];
  const int*   tar  = (const int*)d_in[4];
  const float* W    = (const float*)d_in[5];
  const float* b    = (const float*)d_in[6];
  float* out = (float*)d_out;

  const size_t packed_words = (size_t)N_NODES * WPR;       // per matrix
  const size_t need = 3 * packed_words * sizeof(u64)
                    + 3 * N_NODES * sizeof(float)
                    + N_NODES * sizeof(int);

  if (ws_size >= need) {
    u64* p0 = (u64*)d_ws;
    u64* p1 = p0 + packed_words;
    u64* p2 = p1 + packed_words;
    float* yn  = (float*)(p2 + packed_words);
    int* flags = (int*)(yn + 3 * N_NODES);

    k_ynode   <<<(N_NODES + 3) / 4, 256, 0, stream>>>(x, W, yn, flags);
    k_setflags<<<(2 * N_EDGES + 255) / 256, 256, 0, stream>>>(tar, flags);
    k_bitpack <<<(3 * N_NODES + 3) / 4, 256, 0, stream>>>(a01, a1, a012, flags, p0, p1, p2);
    k_edge    <<<(N_EDGES + 3) / 4, 256, 0, stream>>>(x, tar, p0, p1, p2, yn, W, b, out);
  } else {
    k_edge_direct<<<(N_EDGES + 3) / 4, 256, 0, stream>>>(x, tar, a01, a1, a012, W, b, out);
  }
}

// Round 15
// 957.475 us; speedup vs baseline: 1.0163x; 1.0066x over previous
//
#include <hip/hip_runtime.h>
#include <hip/hip_bf16.h>
#include <stdint.h>

typedef unsigned long long u64;

#define N_NODES 10000
#define D_FEAT  128
#define N_EDGES 8192
#define WPR     160       // u64 words per packed row (all 160 valid in float4 layout)

__device__ __forceinline__ float wave_reduce(float v) {
  #pragma unroll
  for (int o = 32; o > 0; o >>= 1) v += __shfl_xor(v, o, 64);
  return v;
}

// Detect tar_ei element layout per-wave: if the buffer holds int64 (little-endian),
// every odd int32 word is a zero high-word. For genuine int32 indices the odds of
// 64 consecutive odd positions all being 0 are ~0. Returns 2 for int64, 1 for int32.
__device__ __forceinline__ int tar_stride(const int* tar, int lane) {
  int v = tar[2 * lane + 1];
  return (__ballot(v != 0) == 0ull) ? 2 : 1;
}

// K1: per-node projected features yk[n] = x[n,:] . W[(k+1)*128 : (k+2)*128], and zero flags.
__global__ void k_ynode(const float* __restrict__ x, const float* __restrict__ W,
                        float* __restrict__ yn, int* __restrict__ flags) {
  int wid  = (blockIdx.x * blockDim.x + threadIdx.x) >> 6;
  int lane = threadIdx.x & 63;
  if (wid >= N_NODES) return;
  const float* xr = x + (size_t)wid * D_FEAT;
  float x0 = xr[lane], x1 = xr[lane + 64];
  float a0 = x0 * W[128 + lane] + x1 * W[192 + lane];
  float a1 = x0 * W[256 + lane] + x1 * W[320 + lane];
  float a2 = x0 * W[384 + lane] + x1 * W[448 + lane];
  a0 = wave_reduce(a0); a1 = wave_reduce(a1); a2 = wave_reduce(a2);
  if (lane == 0) {
    yn[wid]               = a0;
    yn[N_NODES + wid]     = a1;
    yn[2 * N_NODES + wid] = a2;
    flags[wid] = 0;
  }
}

// K2: mark rows that appear as an edge endpoint (benign write races, all write 1).
__global__ void k_setflags(const int* __restrict__ tar, int* __restrict__ flags) {
  int t    = blockIdx.x * blockDim.x + threadIdx.x;
  int lane = threadIdx.x & 63;
  int stride = tar_stride(tar, lane);
  if (t < 2 * N_EDGES) flags[tar[(size_t)t * stride]] = 1;
}

// K3: bitpack via ballot, ONE BLOCK (4 waves) per (matrix,row).
// Rounds 9/11/12/14: three different per-wave inner loops all pinned at
// ~257us / 2.0 TB/s -> per-wave structure is not the limiter. This version
// changes the CHIP-LEVEL stream topology: 2048 block-contiguous streams
// advancing 8KB/step instead of 5376 wave streams at 1KB granularity.
// Iter i: thread t reads float4[512i+t] and float4[512i+256+t] (8KB/block).
// Wave w owns chunks 8i+w (fa) and 8i+4+w (fb); word 4q+c = ballot(comp c
// of chunk q) -> bit n of word w <-> node 256*(w>>2) + 4n + (w&3).
// Layout identical to round 14; k_edge unchanged.
__global__ __launch_bounds__(256, 8)
void k_bitpack(const float* __restrict__ a0m, const float* __restrict__ a1m,
               const float* __restrict__ a2m, const int* __restrict__ flags,
               u64* __restrict__ p0, u64* __restrict__ p1, u64* __restrict__ p2) {
  int blk = blockIdx.x;                 // 3*N_NODES blocks exactly
  int mat = blk / N_NODES;
  int row = blk - mat * N_NODES;
  if (!flags[row]) return;
  int t    = threadIdx.x;
  int wave = t >> 6;
  int lane = t & 63;
  const float4* src4 = reinterpret_cast<const float4*>(
      (mat == 0 ? a0m : mat == 1 ? a1m : a2m) + (size_t)row * N_NODES);
  u64* dst = (mat == 0 ? p0 : mat == 1 ? p1 : p2) + (size_t)row * WPR;

  #pragma unroll
  for (int i = 0; i < 5; ++i) {
    int i0 = 512 * i + t;               // floats 2048i+4t   (max 9215: always valid)
    int i1 = i0 + 256;                  // floats 2048i+1024+4t (i=4: valid t<196)
    float4 fa = src4[i0];
    float4 fb = (i1 < 2500) ? src4[i1] : make_float4(0.f, 0.f, 0.f, 0.f);
    u64 a0 = __ballot(fa.x != 0.f);
    u64 a1 = __ballot(fa.y != 0.f);
    u64 a2 = __ballot(fa.z != 0.f);
    u64 a3 = __ballot(fa.w != 0.f);
    u64 b0 = __ballot(fb.x != 0.f);
    u64 b1 = __ballot(fb.y != 0.f);
    u64 b2 = __ballot(fb.z != 0.f);
    u64 b3 = __ballot(fb.w != 0.f);
    if (lane == 0) {
      int qa = 8 * i + wave;            // chunk of fa
      int qb = qa + 4;                  // chunk of fb
      u64* da = dst + 4 * qa;
      u64* db = dst + 4 * qb;
      da[0] = a0; da[1] = a1; da[2] = a2; da[3] = a3;
      db[0] = b0; db[1] = b1; db[2] = b2; db[3] = b3;
    }
  }
}

// K4: one wave per edge. AND packed rows, gather yk for set bits, add xij.W0 term, reduce.
// Gather index matches the float4 bit layout: node = ((w>>2)<<8) + 4*bit + (w&3).
__global__ void k_edge(const float* __restrict__ x, const int* __restrict__ tar,
                       const u64* __restrict__ p0, const u64* __restrict__ p1,
                       const u64* __restrict__ p2, const float* __restrict__ yn,
                       const float* __restrict__ W, const float* __restrict__ b,
                       float* __restrict__ out) {
  int e    = (blockIdx.x * blockDim.x + threadIdx.x) >> 6;
  int lane = threadIdx.x & 63;
  int stride = tar_stride(tar, lane);
  if (e >= N_EDGES) return;
  int i = tar[(size_t)e * stride];
  int j = tar[(size_t)(N_EDGES + e) * stride];

  const float* xi = x + (size_t)i * D_FEAT;
  const float* xj = x + (size_t)j * D_FEAT;
  float acc = xi[lane] * xj[lane] * W[lane] + xi[lane + 64] * xj[lane + 64] * W[lane + 64];

  const u64* r0i = p0 + (size_t)i * WPR; const u64* r0j = p0 + (size_t)j * WPR;
  const u64* r1i = p1 + (size_t)i * WPR; const u64* r1j = p1 + (size_t)j * WPR;
  const u64* r2i = p2 + (size_t)i * WPR; const u64* r2j = p2 + (size_t)j * WPR;
  const float* y0 = yn;
  const float* y1 = yn + N_NODES;
  const float* y2 = yn + 2 * N_NODES;

  for (int w = lane; w < WPR; w += 64) {
    u64 m01  = r0i[w] & r0j[w];   // cn_0_1
    u64 m1   = r1i[w] & r1j[w];   // cn_1
    u64 m012 = r2i[w] & r2j[w];   // cn_0_1_2
    u64 m0 = m01  & ~m1;          // cn_0 = cn_0_1 * (1 - cn_1)
    u64 m2 = m012 & ~m01;         // cn_2 = cn_0_1_2 * (1 - cn_0_1)
    int base = (w >> 2) << 8;
    int c    = w & 3;
    while (m0) { int n = __builtin_ctzll(m0); acc += y0[base + (n << 2) + c]; m0 &= m0 - 1; }
    while (m1) { int n = __builtin_ctzll(m1); acc += y1[base + (n << 2) + c]; m1 &= m1 - 1; }
    while (m2) { int n = __builtin_ctzll(m2); acc += y2[base + (n << 2) + c]; m2 &= m2 - 1; }
  }
  acc = wave_reduce(acc);
  if (lane == 0) out[e] = acc + b[0];
}

// Fallback (no workspace): wave per edge, stream float adjacency rows directly.
__global__ void k_edge_direct(const float* __restrict__ x, const int* __restrict__ tar,
                              const float* __restrict__ a0m, const float* __restrict__ a1m,
                              const float* __restrict__ a2m, const float* __restrict__ W,
                              const float* __restrict__ b, float* __restrict__ out) {
  int e    = (blockIdx.x * blockDim.x + threadIdx.x) >> 6;
  int lane = threadIdx.x & 63;
  int stride = tar_stride(tar, lane);
  if (e >= N_EDGES) return;
  int i = tar[(size_t)e * stride];
  int j = tar[(size_t)(N_EDGES + e) * stride];
  const float* xi = x + (size_t)i * D_FEAT;
  const float* xj = x + (size_t)j * D_FEAT;
  float acc = xi[lane] * xj[lane] * W[lane] + xi[lane + 64] * xj[lane + 64] * W[lane + 64];
  const float* r0i = a0m + (size_t)i * N_NODES; const float* r0j = a0m + (size_t)j * N_NODES;
  const float* r1i = a1m + (size_t)i * N_NODES; const float* r1j = a1m + (size_t)j * N_NODES;
  const float* r2i = a2m + (size_t)i * N_NODES; const float* r2j = a2m + (size_t)j * N_NODES;
  for (int n = lane; n < N_NODES; n += 64) {
    float c01  = r0i[n] * r0j[n];
    float c1   = r1i[n] * r1j[n];
    float c012 = r2i[n] * r2j[n];
    float c0 = c01  * (1.f - c1);
    float c2 = c012 * (1.f - c01);
    if (c0 != 0.f || c1 != 0.f || c2 != 0.f) {
      const float* xn = x + (size_t)n * D_FEAT;
      float s = 0.f;
      for (int d = 0; d < D_FEAT; ++d)
        s += (c0 * W[128 + d] + c1 * W[256 + d] + c2 * W[384 + d]) * xn[d];
      acc += s;
    }
  }
  acc = wave_reduce(acc);
  if (lane == 0) out[e] = acc + b[0];
}

extern "C" void kernel_launch(void* const* d_in, const int* in_sizes, int n_in,
                              void* d_out, int out_size, void* d_ws, size_t ws_size,
                              hipStream_t stream) {
  const float* x    = (const float*)d_in[0];
  const float* a01  = (const float*)d_in[1];
  const float* a1   = (const float*)d_in[2];
  const float* a012 = (const float*)d_in[3];
  const int*   tar  = (const int*)d_in[4];
  const float* W    = (const float*)d_in[5];
  const float* b    = (const float*)d_in[6];
  float* out = (float*)d_out;

  const size_t packed_words = (size_t)N_NODES * WPR;       // per matrix
  const size_t need = 3 * packed_words * sizeof(u64)
                    + 3 * N_NODES * sizeof(float)
                    + N_NODES * sizeof(int);

  if (ws_size >= need) {
    u64* p0 = (u64*)d_ws;
    u64* p1 = p0 + packed_words;
    u64* p2 = p1 + packed_words;
    float* yn  = (float*)(p2 + packed_words);
    int* flags = (int*)(yn + 3 * N_NODES);

    k_ynode   <<<(N_NODES + 3) / 4, 256, 0, stream>>>(x, W, yn, flags);
    k_setflags<<<(2 * N_EDGES + 255) / 256, 256, 0, stream>>>(tar, flags);
    k_bitpack <<<3 * N_NODES, 256, 0, stream>>>(a01, a1, a012, flags, p0, p1, p2);
    k_edge    <<<(N_EDGES + 3) / 4, 256, 0, stream>>>(x, tar, p0, p1, p2, yn, W, b, out);
  } else {
    k_edge_direct<<<(N_EDGES + 3) / 4, 256, 0, stream>>>(x, tar, a01, a1, a012, W, b, out);
  }
}

// Round 17
// 951.210 us; speedup vs baseline: 1.0230x; 1.0066x over previous
//
#include <hip/hip_runtime.h>
#include <hip/hip_bf16.h>
#include <stdint.h>

typedef unsigned long long u64;

#define N_NODES 10000
#define D_FEAT  128
#define N_EDGES 8192
#define WPR     160       // u64 words per packed row (all 160 valid in float4 layout)

#define GLOBAL_AS __attribute__((address_space(1)))
#define LDS_AS    __attribute__((address_space(3)))

__device__ __forceinline__ float wave_reduce(float v) {
  #pragma unroll
  for (int o = 32; o > 0; o >>= 1) v += __shfl_xor(v, o, 64);
  return v;
}

// Detect tar_ei element layout per-wave: if the buffer holds int64 (little-endian),
// every odd int32 word is a zero high-word. For genuine int32 indices the odds of
// 64 consecutive odd positions all being 0 are ~0. Returns 2 for int64, 1 for int32.
__device__ __forceinline__ int tar_stride(const int* tar, int lane) {
  int v = tar[2 * lane + 1];
  return (__ballot(v != 0) == 0ull) ? 2 : 1;
}

// K1: per-node projected features yk[n] = x[n,:] . W[(k+1)*128 : (k+2)*128], and zero flags.
__global__ void k_ynode(const float* __restrict__ x, const float* __restrict__ W,
                        float* __restrict__ yn, int* __restrict__ flags) {
  int wid  = (blockIdx.x * blockDim.x + threadIdx.x) >> 6;
  int lane = threadIdx.x & 63;
  if (wid >= N_NODES) return;
  const float* xr = x + (size_t)wid * D_FEAT;
  float x0 = xr[lane], x1 = xr[lane + 64];
  float a0 = x0 * W[128 + lane] + x1 * W[192 + lane];
  float a1 = x0 * W[256 + lane] + x1 * W[320 + lane];
  float a2 = x0 * W[384 + lane] + x1 * W[448 + lane];
  a0 = wave_reduce(a0); a1 = wave_reduce(a1); a2 = wave_reduce(a2);
  if (lane == 0) {
    yn[wid]               = a0;
    yn[N_NODES + wid]     = a1;
    yn[2 * N_NODES + wid] = a2;
    flags[wid] = 0;
  }
}

// K2: mark rows that appear as an edge endpoint (benign write races, all write 1).
__global__ void k_setflags(const int* __restrict__ tar, int* __restrict__ flags) {
  int t    = blockIdx.x * blockDim.x + threadIdx.x;
  int lane = threadIdx.x & 63;
  int stride = tar_stride(tar, lane);
  if (t < 2 * N_EDGES) flags[tar[(size_t)t * stride]] = 1;
}

// K3: bitpack via global_load_lds (async DMA to LDS) + ballot.
// Rounds 9/11/12/14/15: four register-path variants all pinned at ~250-260us /
// ~2 TB/s HBM. Root-cause candidate: <=2 outstanding loads/wave (values must
// sit in VGPRs until ballot consumes them; regalloc refused deeper batches).
// global_load_lds queues 16B/lane requests with ZERO VGPR cost: 10 per wave
// back-to-back -> 40KB in flight per block, 160KB per CU at 4 blocks/CU.
// LDS float p = it*1024 + wave*256 + lane*4  =>  chunk q = p/256 = 4*it+wave,
// so wave w stages AND packs exactly chunks {4i+w} -> no __syncthreads needed,
// only s_waitcnt vmcnt(0). Word layout identical to rounds 14/15
// (word 4q+c = ballot(comp c of chunk q); bit n of word w <-> node
// 256*(w>>2)+4n+(w&3)); k_edge unchanged. Chunk 39 lanes>=4 masked; tail
// global addresses clamped to float 9996 so row 9999 stays in-bounds.
__global__ __launch_bounds__(256, 4)
void k_bitpack(const float* __restrict__ a0m, const float* __restrict__ a1m,
               const float* __restrict__ a2m, const int* __restrict__ flags,
               u64* __restrict__ p0, u64* __restrict__ p1, u64* __restrict__ p2) {
  __shared__ __align__(16) float smem[10240];   // 40960 B -> 4 blocks/CU
  int blk = blockIdx.x;                 // 3*N_NODES blocks exactly
  int mat = blk / N_NODES;
  int row = blk - mat * N_NODES;
  if (!flags[row]) return;
  int t    = threadIdx.x;
  int wave = t >> 6;
  int lane = t & 63;
  const float* src = (mat == 0 ? a0m : mat == 1 ? a1m : a2m) + (size_t)row * N_NODES;
  u64* dst = (mat == 0 ? p0 : mat == 1 ? p1 : p2) + (size_t)row * WPR;

  // Stage: 9 full iters (floats 0..9215) + clamped tail (floats 9216..9999).
  #pragma unroll
  for (int it = 0; it < 9; ++it) {
    int off = it * 1024 + wave * 256 + lane * 4;      // float index, 16B per lane
    __builtin_amdgcn_global_load_lds(
        (const GLOBAL_AS void*)(src + off),
        (LDS_AS void*)(&smem[it * 1024 + wave * 256]), 16, 0, 0);
  }
  {
    int off = 9216 + t * 4;
    if (off > 9996) off = 9996;                       // clamp: stay inside the row
    __builtin_amdgcn_global_load_lds(
        (const GLOBAL_AS void*)(src + off),
        (LDS_AS void*)(&smem[9216 + wave * 256]), 16, 0, 0);
  }
  asm volatile("s_waitcnt vmcnt(0)" ::: "memory");

  // Pack: wave w owns chunks 4k+w (k=0..9) — exactly what it staged.
  #pragma unroll
  for (int k = 0; k < 10; ++k) {
    int chunk = 4 * k + wave;
    float4 f = *reinterpret_cast<float4*>(&smem[chunk * 256 + lane * 4]);
    bool valid = (chunk != 39) || (lane < 4);         // floats >=10000 are not real
    u64 b0 = __ballot(valid && f.x != 0.f);
    u64 b1 = __ballot(valid && f.y != 0.f);
    u64 b2 = __ballot(valid && f.z != 0.f);
    u64 b3 = __ballot(valid && f.w != 0.f);
    if (lane == 0) {
      u64* d = dst + 4 * chunk;
      d[0] = b0; d[1] = b1; d[2] = b2; d[3] = b3;
    }
  }
}

// K4: one wave per edge. AND packed rows, gather yk for set bits, add xij.W0 term, reduce.
// Gather index matches the float4 bit layout: node = ((w>>2)<<8) + 4*bit + (w&3).
__global__ void k_edge(const float* __restrict__ x, const int* __restrict__ tar,
                       const u64* __restrict__ p0, const u64* __restrict__ p1,
                       const u64* __restrict__ p2, const float* __restrict__ yn,
                       const float* __restrict__ W, const float* __restrict__ b,
                       float* __restrict__ out) {
  int e    = (blockIdx.x * blockDim.x + threadIdx.x) >> 6;
  int lane = threadIdx.x & 63;
  int stride = tar_stride(tar, lane);
  if (e >= N_EDGES) return;
  int i = tar[(size_t)e * stride];
  int j = tar[(size_t)(N_EDGES + e) * stride];

  const float* xi = x + (size_t)i * D_FEAT;
  const float* xj = x + (size_t)j * D_FEAT;
  float acc = xi[lane] * xj[lane] * W[lane] + xi[lane + 64] * xj[lane + 64] * W[lane + 64];

  const u64* r0i = p0 + (size_t)i * WPR; const u64* r0j = p0 + (size_t)j * WPR;
  const u64* r1i = p1 + (size_t)i * WPR; const u64* r1j = p1 + (size_t)j * WPR;
  const u64* r2i = p2 + (size_t)i * WPR; const u64* r2j = p2 + (size_t)j * WPR;
  const float* y0 = yn;
  const float* y1 = yn + N_NODES;
  const float* y2 = yn + 2 * N_NODES;

  for (int w = lane; w < WPR; w += 64) {
    u64 m01  = r0i[w] & r0j[w];   // cn_0_1
    u64 m1   = r1i[w] & r1j[w];   // cn_1
    u64 m012 = r2i[w] & r2j[w];   // cn_0_1_2
    u64 m0 = m01  & ~m1;          // cn_0 = cn_0_1 * (1 - cn_1)
    u64 m2 = m012 & ~m01;         // cn_2 = cn_0_1_2 * (1 - cn_0_1)
    int base = (w >> 2) << 8;
    int c    = w & 3;
    while (m0) { int n = __builtin_ctzll(m0); acc += y0[base + (n << 2) + c]; m0 &= m0 - 1; }
    while (m1) { int n = __builtin_ctzll(m1); acc += y1[base + (n << 2) + c]; m1 &= m1 - 1; }
    while (m2) { int n = __builtin_ctzll(m2); acc += y2[base + (n << 2) + c]; m2 &= m2 - 1; }
  }
  acc = wave_reduce(acc);
  if (lane == 0) out[e] = acc + b[0];
}

// Fallback (no workspace): wave per edge, stream float adjacency rows directly.
__global__ void k_edge_direct(const float* __restrict__ x, const int* __restrict__ tar,
                              const float* __restrict__ a0m, const float* __restrict__ a1m,
                              const float* __restrict__ a2m, const float* __restrict__ W,
                              const float* __restrict__ b, float* __restrict__ out) {
  int e    = (blockIdx.x * blockDim.x + threadIdx.x) >> 6;
  int lane = threadIdx.x & 63;
  int stride = tar_stride(tar, lane);
  if (e >= N_EDGES) return;
  int i = tar[(size_t)e * stride];
  int j = tar[(size_t)(N_EDGES + e) * stride];
  const float* xi = x + (size_t)i * D_FEAT;
  const float* xj = x + (size_t)j * D_FEAT;
  float acc = xi[lane] * xj[lane] * W[lane] + xi[lane + 64] * xj[lane + 64] * W[lane + 64];
  const float* r0i = a0m + (size_t)i * N_NODES; const float* r0j = a0m + (size_t)j * N_NODES;
  const float* r1i = a1m + (size_t)i * N_NODES; const float* r1j = a1m + (size_t)j * N_NODES;
  const float* r2i = a2m + (size_t)i * N_NODES; const float* r2j = a2m + (size_t)j * N_NODES;
  for (int n = lane; n < N_NODES; n += 64) {
    float c01  = r0i[n] * r0j[n];
    float c1   = r1i[n] * r1j[n];
    float c012 = r2i[n] * r2j[n];
    float c0 = c01  * (1.f - c1);
    float c2 = c012 * (1.f - c01);
    if (c0 != 0.f || c1 != 0.f || c2 != 0.f) {
      const float* xn = x + (size_t)n * D_FEAT;
      float s = 0.f;
      for (int d = 0; d < D_FEAT; ++d)
        s += (c0 * W[128 + d] + c1 * W[256 + d] + c2 * W[384 + d]) * xn[d];
      acc += s;
    }
  }
  acc = wave_reduce(acc);
  if (lane == 0) out[e] = acc + b[0];
}

extern "C" void kernel_launch(void* const* d_in, const int* in_sizes, int n_in,
                              void* d_out, int out_size, void* d_ws, size_t ws_size,
                              hipStream_t stream) {
  const float* x    = (const float*)d_in[0];
  const float* a01  = (const float*)d_in[1];
  const float* a1   = (const float*)d_in[2];
  const float* a012 = (const float*)d_in[3];
  const int*   tar  = (const int*)d_in[4];
  const float* W    = (const float*)d_in[5];
  const float* b    = (const float*)d_in[6];
  float* out = (float*)d_out;

  const size_t packed_words = (size_t)N_NODES * WPR;       // per matrix
  const size_t need = 3 * packed_words * sizeof(u64)
                    + 3 * N_NODES * sizeof(float)
                    + N_NODES * sizeof(int);

  if (ws_size >= need) {
    u64* p0 = (u64*)d_ws;
    u64* p1 = p0 + packed_words;
    u64* p2 = p1 + packed_words;
    float* yn  = (float*)(p2 + packed_words);
    int* flags = (int*)(yn + 3 * N_NODES);

    k_ynode   <<<(N_NODES + 3) / 4, 256, 0, stream>>>(x, W, yn, flags);
    k_setflags<<<(2 * N_EDGES + 255) / 256, 256, 0, stream>>>(tar, flags);
    k_bitpack <<<3 * N_NODES, 256, 0, stream>>>(a01, a1, a012, flags, p0, p1, p2);
    k_edge    <<<(N_EDGES + 3) / 4, 256, 0, stream>>>(x, tar, p0, p1, p2, yn, W, b, out);
  } else {
    k_edge_direct<<<(N_EDGES + 3) / 4, 256, 0, stream>>>(x, tar, a01, a1, a012, W, b, out);
  }
}